// Round 1
// baseline (434.412 us; speedup 1.0000x reference)
//
#include <hip/hip_runtime.h>

#define DIMC 1024
#define NSEQ 8192
#define DH 64

typedef __attribute__((ext_vector_type(8))) short short8;
typedef __attribute__((ext_vector_type(4))) float f32x4;

__device__ __forceinline__ short f2bf(float f) {
  union { float f; unsigned u; } v; v.f = f;
  unsigned r = v.u + 0x7FFFu + ((v.u >> 16) & 1u);
  return (short)(r >> 16);
}

__device__ __forceinline__ void gload_lds16(const void* g, void* l) {
  __builtin_amdgcn_global_load_lds(
      (const __attribute__((address_space(1))) void*)g,
      (__attribute__((address_space(3))) void*)l, 16, 0, 0);
}

// ---------------- Stage 1: Gram matrices G[b,h] = X^T X (partials) ----------
// grid (32 chunks, 64 bh), block 64 (1 wave). 8x8 register tile/thread:
// 64B LDS per 64 FMA -> LDS/VALU balanced.
__global__ __launch_bounds__(64) void gram_kernel(const float* __restrict__ x,
                                                  float* __restrict__ Gpart) {
  int chunk = blockIdx.x, bh = blockIdx.y;
  int b = bh >> 4, h = bh & 15;
  int t = threadIdx.x;
  __shared__ __align__(16) float rows[16 * 64];
  const float* xb = x + ((size_t)b * NSEQ) * DIMC + h * DH;
  int d0 = (t >> 3) * 8, e0 = (t & 7) * 8;
  float acc[8][8] = {};
  for (int it = 0; it < 16; it++) {
    int nbase = chunk * 256 + it * 16;
    float4 v[4];
#pragma unroll
    for (int i = 0; i < 4; i++) {
      int f4 = i * 64 + t;
      v[i] = *(const float4*)(xb + (size_t)(nbase + (f4 >> 4)) * DIMC + (f4 & 15) * 4);
    }
    __syncthreads();
#pragma unroll
    for (int i = 0; i < 4; i++) ((float4*)rows)[i * 64 + t] = v[i];
    __syncthreads();
#pragma unroll
    for (int r = 0; r < 16; r++) {
      float xd[8], xe[8];
      *(float4*)&xd[0] = *(const float4*)&rows[r * 64 + d0];
      *(float4*)&xd[4] = *(const float4*)&rows[r * 64 + d0 + 4];
      *(float4*)&xe[0] = *(const float4*)&rows[r * 64 + e0];
      *(float4*)&xe[4] = *(const float4*)&rows[r * 64 + e0 + 4];
#pragma unroll
      for (int i = 0; i < 8; i++)
#pragma unroll
        for (int j = 0; j < 8; j++) acc[i][j] = fmaf(xd[i], xe[j], acc[i][j]);
    }
  }
  float* gp = Gpart + (size_t)chunk * (64 * 4096) + (size_t)bh * 4096;
#pragma unroll
  for (int i = 0; i < 8; i++)
#pragma unroll
    for (int j = 0; j < 8; j++) gp[(d0 + i) * 64 + e0 + j] = acc[i][j];
}

// ---------------- Stage 1b: reduce 32 partials -> G ----------
__global__ void reduce_g(const float* __restrict__ Gpart, float* __restrict__ G) {
  int i = blockIdx.x * 256 + threadIdx.x;  // 0..262143
  float s = 0.f;
#pragma unroll
  for (int p = 0; p < 32; p++) s += Gpart[(size_t)p * (64 * 4096) + i];
  G[i] = s;
}

// ---------------- Stage 2: WbigT[b][c][k] = (Wq^T Wk G Wv^T /N  Wo_h^T)^T ----
// grid (64 bh, 4 c-quarters), block 256. Small ops redundant per quarter.
__global__ __launch_bounds__(256) void combine_kernel(
    const float* __restrict__ G, const float* __restrict__ Wq,
    const float* __restrict__ Wk, const float* __restrict__ Wv,
    const float* __restrict__ Wo, short* __restrict__ WbigT) {
  int bh = blockIdx.x, qt = blockIdx.y;
  int b = bh >> 4, h = bh & 15;
  int t = threadIdx.x;
  __shared__ __align__(16) float sG[4096];  // G, later T2
  __shared__ __align__(16) float sW[4096];  // current weight
  __shared__ __align__(16) float sA[4096];  // T1
  __shared__ __align__(16) float sM[4096];  // M

  for (int i = t; i < 4096; i += 256) sG[i] = G[(size_t)bh * 4096 + i];
  for (int i = t; i < 4096; i += 256) sW[i] = Wk[i];
  __syncthreads();

  int d0 = (t >> 4) * 4, e0 = (t & 15) * 4;
  // T1 = Wk * G  -> sA
  {
    float a[4][4] = {};
    for (int fg = 0; fg < 16; fg++) {
      float wk[4][4], g4[4][4];
#pragma unroll
      for (int i = 0; i < 4; i++) *(float4*)wk[i] = *(const float4*)&sW[(d0 + i) * 64 + fg * 4];
#pragma unroll
      for (int ff = 0; ff < 4; ff++) *(float4*)g4[ff] = *(const float4*)&sG[(fg * 4 + ff) * 64 + e0];
#pragma unroll
      for (int i = 0; i < 4; i++)
#pragma unroll
        for (int ff = 0; ff < 4; ff++)
#pragma unroll
          for (int j = 0; j < 4; j++) a[i][j] = fmaf(wk[i][ff], g4[ff][j], a[i][j]);
    }
#pragma unroll
    for (int i = 0; i < 4; i++)
#pragma unroll
      for (int j = 0; j < 4; j++) sA[(d0 + i) * 64 + e0 + j] = a[i][j];
  }
  __syncthreads();
  for (int i = t; i < 4096; i += 256) sW[i] = Wv[i];
  __syncthreads();
  // T2 = T1 * Wv^T -> sG   (f-group rotated by lane to break 16-way conflicts)
  {
    float a[4][4] = {};
    for (int fgi = 0; fgi < 16; fgi++) {
      int fg = (fgi + (t & 15)) & 15;
      float t1[4][4], wv[4][4];
#pragma unroll
      for (int i = 0; i < 4; i++) *(float4*)t1[i] = *(const float4*)&sA[(d0 + i) * 64 + fg * 4];
#pragma unroll
      for (int j = 0; j < 4; j++) *(float4*)wv[j] = *(const float4*)&sW[(e0 + j) * 64 + fg * 4];
#pragma unroll
      for (int i = 0; i < 4; i++)
#pragma unroll
        for (int j = 0; j < 4; j++)
#pragma unroll
          for (int ff = 0; ff < 4; ff++) a[i][j] = fmaf(t1[i][ff], wv[j][ff], a[i][j]);
    }
    __syncthreads();  // everyone done reading old sG before overwrite
#pragma unroll
    for (int i = 0; i < 4; i++)
#pragma unroll
      for (int j = 0; j < 4; j++) sG[(d0 + i) * 64 + e0 + j] = a[i][j];
  }
  __syncthreads();
  for (int i = t; i < 4096; i += 256) sW[i] = Wq[i];
  __syncthreads();
  // M = Wq^T * T2 / N -> sM
  {
    float a[4][4] = {};
    for (int f = 0; f < 64; f++) {
      float wq[4], t2[4];
      *(float4*)wq = *(const float4*)&sW[f * 64 + d0];
      *(float4*)t2 = *(const float4*)&sG[f * 64 + e0];
#pragma unroll
      for (int i = 0; i < 4; i++)
#pragma unroll
        for (int j = 0; j < 4; j++) a[i][j] = fmaf(wq[i], t2[j], a[i][j]);
    }
#pragma unroll
    for (int i = 0; i < 4; i++)
#pragma unroll
      for (int j = 0; j < 4; j++) sM[(d0 + i) * 64 + e0 + j] = a[i][j] * (1.0f / 8192.0f);
  }
  __syncthreads();
  // W2[d,c] = sum_e M[d,e] Wo[c, h*64+e]; write WbigT[b][c][h*64+d]
  int dd0 = (t & 15) * 4, cl0 = (t >> 4) * 4;  // d lane-fast for coalesced stores
  for (int cc = qt * 4; cc < qt * 4 + 4; cc++) {
    int c0 = cc * 64;
    for (int i = t; i < 4096; i += 256)
      sW[i] = Wo[(size_t)(c0 + (i >> 6)) * DIMC + h * DH + (i & 63)];
    __syncthreads();
    float a[4][4] = {};
    for (int egi = 0; egi < 16; egi++) {
      int eg = (egi + (t & 15)) & 15;
      float m4[4][4], wo4[4][4];
#pragma unroll
      for (int i = 0; i < 4; i++) *(float4*)m4[i] = *(const float4*)&sM[(dd0 + i) * 64 + eg * 4];
#pragma unroll
      for (int j = 0; j < 4; j++) *(float4*)wo4[j] = *(const float4*)&sW[(cl0 + j) * 64 + eg * 4];
#pragma unroll
      for (int i = 0; i < 4; i++)
#pragma unroll
        for (int j = 0; j < 4; j++)
#pragma unroll
          for (int ff = 0; ff < 4; ff++) a[i][j] = fmaf(m4[i][ff], wo4[j][ff], a[i][j]);
    }
#pragma unroll
    for (int j = 0; j < 4; j++)
#pragma unroll
      for (int i = 0; i < 4; i++)
        WbigT[((size_t)b << 20) + (size_t)(c0 + cl0 + j) * DIMC + h * DH + dd0 + i] =
            f2bf(a[i][j]);
    __syncthreads();
  }
}

// ---------------- Stage 3: out = x @ Wbig[b] + bo  (bf16 MFMA, m97 structure)
// 128x128 tile, BK=32, B via global_load_lds x16, A fp32->bf16 convert+ds_write.
__global__ __launch_bounds__(256, 2) void gemm_kernel(
    const float* __restrict__ x, const short* __restrict__ WbigT,
    const float* __restrict__ bo, float* __restrict__ out) {
  int bid = blockIdx.x;
  // XCD-aware swizzle: 8 XCDs x 8 groups x (4 m_in x 8 n) — ~4MB L2 footprint/XCD
  int xcd = bid & 7, r = bid >> 3;
  int g = r >> 5, q = r & 31;
  int m_blk = g * 32 + xcd * 4 + (q >> 3);
  int n_blk = q & 7;
  int b = m_blk >> 6;
  int row0 = m_blk * 128;
  int c0 = n_blk * 128;

  __shared__ __align__(16) short As[128 * 32];
  __shared__ __align__(16) short Bs[128 * 32];

  int t = threadIdx.x;
  int lane = t & 63, wave = t >> 6;
  int wm = wave >> 1, wn = wave & 1;
  int quad = lane >> 4, ln = lane & 15;

  f32x4 acc[4][4];
#pragma unroll
  for (int i = 0; i < 4; i++)
#pragma unroll
    for (int j = 0; j < 4; j++) acc[i][j] = (f32x4){0.f, 0.f, 0.f, 0.f};

  const short* Bbase = WbigT + ((size_t)b << 20);

  for (int kt = 0; kt < 32; kt++) {
    int k0 = kt * 32;
    __syncthreads();
    // B tile: async 16B direct-to-LDS, [c][k] rows of 64B
#pragma unroll
    for (int L = 0; L < 2; L++) {
      int elem = (wave * 2 + L) * 512 + lane * 8;
      int crow = elem >> 5, koff = elem & 31;
      gload_lds16(Bbase + (size_t)(c0 + crow) * DIMC + k0 + koff, &Bs[elem]);
    }
    // A tile: fp32 load -> bf16 pack -> ds_write_b128, [m][k] rows of 64B
#pragma unroll
    for (int qq = 0; qq < 2; qq++) {
      int elem = qq * 2048 + wave * 512 + lane * 8;
      int m = elem >> 5, kk = elem & 31;
      const float* gp = x + (size_t)(row0 + m) * DIMC + k0 + kk;
      float4 v0 = *(const float4*)gp;
      float4 v1 = *(const float4*)(gp + 4);
      short8 pk;
      pk[0] = f2bf(v0.x); pk[1] = f2bf(v0.y); pk[2] = f2bf(v0.z); pk[3] = f2bf(v0.w);
      pk[4] = f2bf(v1.x); pk[5] = f2bf(v1.y); pk[6] = f2bf(v1.z); pk[7] = f2bf(v1.w);
      *(short8*)&As[elem] = pk;
    }
    __syncthreads();
    short8 afrag[4], bfrag[4];
#pragma unroll
    for (int i = 0; i < 4; i++) {
      afrag[i] = *(const short8*)&As[(wm * 64 + i * 16 + ln) * 32 + quad * 8];
      bfrag[i] = *(const short8*)&Bs[(wn * 64 + i * 16 + ln) * 32 + quad * 8];
    }
#pragma unroll
    for (int i = 0; i < 4; i++)
#pragma unroll
      for (int j = 0; j < 4; j++)
        acc[i][j] = __builtin_amdgcn_mfma_f32_16x16x32_bf16(afrag[i], bfrag[j], acc[i][j], 0, 0, 0);
  }

  // epilogue: C/D layout col=lane&15, row=quad*4+reg (m89-verified)
  float bov[4];
#pragma unroll
  for (int j = 0; j < 4; j++) bov[j] = bo[c0 + wn * 64 + j * 16 + ln];
#pragma unroll
  for (int i = 0; i < 4; i++)
#pragma unroll
    for (int j = 0; j < 4; j++) {
      int col = c0 + wn * 64 + j * 16 + ln;
#pragma unroll
      for (int rr = 0; rr < 4; rr++) {
        int row = row0 + wm * 64 + i * 16 + quad * 4 + rr;
        out[(size_t)row * DIMC + col] = acc[i][j][rr] + bov[j];
      }
    }
}

extern "C" void kernel_launch(void* const* d_in, const int* in_sizes, int n_in,
                              void* d_out, int out_size, void* d_ws, size_t ws_size,
                              hipStream_t stream) {
  const float* x  = (const float*)d_in[0];
  const float* Wq = (const float*)d_in[1];
  const float* Wk = (const float*)d_in[2];
  const float* Wv = (const float*)d_in[3];
  const float* Wo = (const float*)d_in[4];
  const float* bo = (const float*)d_in[5];
  float* out = (float*)d_out;

  // workspace layout: Gpart 32 MiB | G 1 MiB | WbigT 8 MiB  (needs 41 MiB)
  float* Gpart = (float*)d_ws;
  float* G     = (float*)((char*)d_ws + ((size_t)32 << 20));
  short* WbigT = (short*)((char*)d_ws + ((size_t)33 << 20));
  (void)in_sizes; (void)n_in; (void)out_size; (void)ws_size;

  gram_kernel<<<dim3(32, 64), 64, 0, stream>>>(x, Gpart);
  reduce_g<<<1024, 256, 0, stream>>>(Gpart, G);
  combine_kernel<<<dim3(64, 4), 256, 0, stream>>>(G, Wq, Wk, Wv, Wo, WbigT);
  gemm_kernel<<<2048, 256, 0, stream>>>(x, WbigT, bo, out);
}